// Round 1
// baseline (144.811 us; speedup 1.0000x reference)
//
#include <hip/hip_runtime.h>
#include <hip/hip_bf16.h>
#include <cstdint>
#include <cstddef>

#define Nn 8
#define Cc 128
#define Oo 128
#define Hh 64
#define Ww 64
#define LL (Hh * Ww)
#define KP 9

typedef __attribute__((ext_vector_type(8))) short short8;
typedef __attribute__((ext_vector_type(4))) float floatx4;

__device__ __forceinline__ unsigned short f2bf(float f) {
  unsigned int u = __float_as_uint(f);
  u += 0x7fffu + ((u >> 16) & 1u);   // round-to-nearest-even
  return (unsigned short)(u >> 16);
}

// x[n][c][h][w] fp32  ->  xt[n][h][w][c] bf16 (channels-last for contiguous A staging)
__global__ __launch_bounds__(256) void prep_x(const float* __restrict__ x,
                                              unsigned short* __restrict__ xt) {
  __shared__ float tile[Cc][Ww + 1];
  const int n = blockIdx.x >> 6;
  const int h = blockIdx.x & 63;
  const float* src = x + (size_t)n * Cc * LL + (size_t)h * Ww;
  const int t = threadIdx.x;
#pragma unroll
  for (int it = 0; it < 8; ++it) {
    const int idx = t + it * 256;          // 0..2047
    const int c = idx >> 4;
    const int w4 = (idx & 15) << 2;
    const float4 v = *reinterpret_cast<const float4*>(src + (size_t)c * LL + w4);
    tile[c][w4 + 0] = v.x; tile[c][w4 + 1] = v.y;
    tile[c][w4 + 2] = v.z; tile[c][w4 + 3] = v.w;
  }
  __syncthreads();
  unsigned short* dst = xt + (size_t)((n * Hh + h) * Ww) * Cc;
#pragma unroll
  for (int it = 0; it < 4; ++it) {
    const int idx = t + it * 256;          // 0..1023
    const int w = idx >> 4;
    const int ch = (idx & 15) << 3;
    short8 v;
#pragma unroll
    for (int q = 0; q < 8; ++q)
      ((unsigned short*)&v)[q] = f2bf(tile[ch + q][w]);
    *reinterpret_cast<short8*>(dst + (size_t)w * Cc + ch) = v;
  }
}

// w_b[o][c][ky][kx] fp32  ->  wt[b][kk][o][c] bf16 (c contiguous for B-fragment reads)
__global__ __launch_bounds__(256) void prep_w(const float* __restrict__ w0,
                                              const float* __restrict__ w1,
                                              const float* __restrict__ w2,
                                              unsigned short* __restrict__ wt) {
  const int idx = blockIdx.x * 256 + threadIdx.x;   // 0 .. 3*9*128*128-1
  const int c = idx & 127;
  const int o = (idx >> 7) & 127;
  const int kk = (idx >> 14) % KP;
  const int b = idx / (KP << 14);
  const float* w = (b == 0) ? w0 : (b == 1) ? w1 : w2;
  wt[idx] = f2bf(w[(size_t)(o * Cc + c) * KP + kk]);
}

#define MT 128
#define NT 64
#define LDA 136
#define LDB 136

__global__ __launch_bounds__(256, 2) void conv_main(
    const unsigned short* __restrict__ xt,
    const unsigned short* __restrict__ wt,
    const float* __restrict__ depth,
    const float* __restrict__ fx,
    float* __restrict__ out) {
  __shared__ unsigned short As[MT * LDA];   // 34816 B
  __shared__ unsigned short Bs[NT * LDB];   // 17408 B
  __shared__ unsigned char code[MT * KP];   // 1152 B

  const int g = blockIdx.x;          // 512 blocks
  const int n = g >> 6;
  const int rem = g & 63;
  const int pb = rem >> 1;           // 0..31  -> row pair
  const int ob = (rem & 1) * NT;     // 0 or 64
  const int h0 = pb * 2;

  const int tid = threadIdx.x;
  const int lane = tid & 63;
  const int wave = tid >> 6;
  const int ln15 = lane & 15;
  const int quad = lane >> 4;
  const int m_half = (wave >> 1) * 64;
  const int wc = wave & 1;

  // ---- depth masks: 3-bit code per (pixel m, kernel pos kk) ----
  if (tid < MT) {
    const int m = tid;
    const int h = h0 + (m >> 6);
    const int w = m & 63;
    const float center = depth[n * LL + h * Ww + w];
    const float fxv = fx[n];
    const float grid = center / fxv;     // PIXEL_SIZE*DILATION = 1
    const float half = 0.5f * grid;
#pragma unroll
    for (int kk = 0; kk < KP; ++kk) {
      const int hh = h + kk / 3 - 1;
      const int ww = w + kk % 3 - 1;
      float d = 0.0f;
      if (hh >= 0 && hh < Hh && ww >= 0 && ww < Ww) d = depth[n * LL + hh * Ww + ww];
      const float valid = (d != 0.0f && center != 0.0f) ? 1.0f : 0.0f;
      const float dm = d * valid;
      unsigned int cb = 0u;
      if (fabsf(dm - (center + grid)) <= half) cb |= 1u;
      float m1v = (fabsf(dm - center) <= half) ? 1.0f : 0.0f;
      m1v = m1v + 1.0f - valid;
      if (m1v > 1.0f) m1v = 1.0f;
      if (m1v > 0.5f) cb |= 2u;
      if (fabsf(dm - (center - grid)) <= half) cb |= 4u;
      code[m * KP + kk] = (unsigned char)cb;
    }
  }

  const floatx4 zf4 = {0.f, 0.f, 0.f, 0.f};
  const short8 zs8 = {0, 0, 0, 0, 0, 0, 0, 0};
  floatx4 acc[4][2];
#pragma unroll
  for (int i = 0; i < 4; ++i)
#pragma unroll
    for (int j = 0; j < 2; ++j) acc[i][j] = zf4;

  int mi[4];
#pragma unroll
  for (int i = 0; i < 4; ++i) mi[i] = m_half + i * 16 + ln15;

  for (int kk = 0; kk < KP; ++kk) {
    const int dy = kk / 3 - 1;
    const int dx = kk % 3 - 1;
    __syncthreads();                       // prior reads of As/Bs done
    // ---- stage A slice: As[m][c] = x[n, c, p(m,kk)] bf16 ----
#pragma unroll
    for (int it = 0; it < 8; ++it) {
      const int idx = tid + it * 256;      // 0..2047
      const int m = idx >> 4;
      const int ch = (idx & 15) << 3;
      const int h = h0 + (m >> 6);
      const int w = m & 63;
      const int hh = h + dy;
      const int ww = w + dx;
      float4 v = make_float4(0.f, 0.f, 0.f, 0.f);
      if (hh >= 0 && hh < Hh && ww >= 0 && ww < Ww)
        v = *reinterpret_cast<const float4*>(xt + (size_t)((n * Hh + hh) * Ww + ww) * Cc + ch);
      *reinterpret_cast<float4*>(&As[m * LDA + ch]) = v;
    }
    __syncthreads();

    // hoist raw A fragments (reused by all 3 branches)
    short8 araw[4][4];
#pragma unroll
    for (int c0 = 0; c0 < 4; ++c0)
#pragma unroll
      for (int i = 0; i < 4; ++i)
        araw[c0][i] = *reinterpret_cast<const short8*>(
            &As[(m_half + i * 16 + ln15) * LDA + c0 * 32 + quad * 8]);

    unsigned int cd[4];
#pragma unroll
    for (int i = 0; i < 4; ++i) cd[i] = code[mi[i] * KP + kk];

    for (int b = 0; b < 3; ++b) {
      if (b > 0) __syncthreads();
      // ---- stage B tile: Bs[o_local][c] = wt[b][kk][ob+o_local][c] ----
#pragma unroll
      for (int it = 0; it < 4; ++it) {
        const int idx = tid + it * 256;    // 0..1023
        const int o = idx >> 4;
        const int ch = (idx & 15) << 3;
        const float4 v = *reinterpret_cast<const float4*>(
            wt + (size_t)((b * KP + kk) * Oo + ob + o) * Cc + ch);
        *reinterpret_cast<float4*>(&Bs[o * LDB + ch]) = v;
      }
      __syncthreads();

#pragma unroll
      for (int c0 = 0; c0 < 4; ++c0) {
        short8 bfrag[2];
#pragma unroll
        for (int j = 0; j < 2; ++j)
          bfrag[j] = *reinterpret_cast<const short8*>(
              &Bs[(wc * 32 + j * 16 + ln15) * LDB + c0 * 32 + quad * 8]);
#pragma unroll
        for (int i = 0; i < 4; ++i) {
          short8 af = araw[c0][i];
          if (((cd[i] >> b) & 1u) == 0u) af = zs8;   // per-lane select (mask per m-row)
#pragma unroll
          for (int j = 0; j < 2; ++j)
            acc[i][j] = __builtin_amdgcn_mfma_f32_16x16x32_bf16(af, bfrag[j], acc[i][j], 0, 0, 0);
        }
      }
    }
  }

  // ---- epilogue: D row = m (quad*4+reg), col = o (lane&15) ----
#pragma unroll
  for (int i = 0; i < 4; ++i) {
    const int m = m_half + i * 16 + quad * 4;
    const int h = h0 + (m >> 6);
    const int w = m & 63;
#pragma unroll
    for (int j = 0; j < 2; ++j) {
      const int o = ob + wc * 32 + j * 16 + ln15;
      float* dst = out + (size_t)(n * Oo + o) * LL + h * Ww + w;
      *reinterpret_cast<floatx4*>(dst) = acc[i][j];
    }
  }
}

extern "C" void kernel_launch(void* const* d_in, const int* in_sizes, int n_in,
                              void* d_out, int out_size, void* d_ws, size_t ws_size,
                              hipStream_t stream) {
  const float* x     = (const float*)d_in[0];
  const float* depth = (const float*)d_in[1];
  const float* fx    = (const float*)d_in[2];
  const float* w0    = (const float*)d_in[3];
  const float* w1    = (const float*)d_in[4];
  const float* w2    = (const float*)d_in[5];
  float* out = (float*)d_out;

  // ws layout: xt (8*64*64*128 bf16 = 8 MB) | wt (3*9*128*128 bf16 = 0.88 MB)
  unsigned short* xt = (unsigned short*)d_ws;
  unsigned short* wt = xt + (size_t)Nn * Hh * Ww * Cc;

  prep_x<<<Nn * Hh, 256, 0, stream>>>(x, xt);
  prep_w<<<(3 * KP * Oo * Cc) / 256, 256, 0, stream>>>(w0, w1, w2, wt);
  conv_main<<<512, 256, 0, stream>>>(xt, wt, depth, fx, out);
}

// Round 2
// 139.653 us; speedup vs baseline: 1.0369x; 1.0369x over previous
//
#include <hip/hip_runtime.h>
#include <hip/hip_bf16.h>
#include <cstdint>
#include <cstddef>

#define Nn 8
#define Cc 128
#define Oo 128
#define Hh 64
#define Ww 64
#define LL (Hh * Ww)
#define KP 9

typedef __attribute__((ext_vector_type(8))) short short8;
typedef __attribute__((ext_vector_type(4))) float floatx4;

__device__ __forceinline__ unsigned short f2bf(float f) {
  unsigned int u = __float_as_uint(f);
  u += 0x7fffu + ((u >> 16) & 1u);   // round-to-nearest-even
  return (unsigned short)(u >> 16);
}

// Fused prep:
//  blocks [0, 512):   x[n][c][h][w] fp32 -> xt[n][h][w][c] bf16
//  blocks [512, 896): w_b[o][c][3][3] fp32 -> wt[b][kk][o][c] bf16 (coalesced via LDS)
__global__ __launch_bounds__(256) void prep_all(const float* __restrict__ x,
                                                const float* __restrict__ w0,
                                                const float* __restrict__ w1,
                                                const float* __restrict__ w2,
                                                unsigned short* __restrict__ xt,
                                                unsigned short* __restrict__ wt) {
  __shared__ float tile[Cc][Ww + 1];
  __shared__ unsigned short wl[Cc * KP];
  const int bid = blockIdx.x;
  const int t = threadIdx.x;
  if (bid < Nn * Hh) {
    const int n = bid >> 6;
    const int h = bid & 63;
    const float* src = x + (size_t)n * Cc * LL + (size_t)h * Ww;
#pragma unroll
    for (int it = 0; it < 8; ++it) {
      const int idx = t + it * 256;          // 0..2047
      const int c = idx >> 4;
      const int w4 = (idx & 15) << 2;
      const float4 v = *reinterpret_cast<const float4*>(src + (size_t)c * LL + w4);
      tile[c][w4 + 0] = v.x; tile[c][w4 + 1] = v.y;
      tile[c][w4 + 2] = v.z; tile[c][w4 + 3] = v.w;
    }
    __syncthreads();
    unsigned short* dst = xt + (size_t)((n * Hh + h) * Ww) * Cc;
#pragma unroll
    for (int it = 0; it < 4; ++it) {
      const int idx = t + it * 256;          // 0..1023
      const int w = idx >> 4;
      const int ch = (idx & 15) << 3;
      short8 v;
#pragma unroll
      for (int q = 0; q < 8; ++q)
        ((unsigned short*)&v)[q] = f2bf(tile[ch + q][w]);
      *reinterpret_cast<short8*>(dst + (size_t)w * Cc + ch) = v;
    }
  } else {
    const int bo = bid - Nn * Hh;            // 0..383
    const int b = bo >> 7;
    const int o = bo & 127;
    const float* w = (b == 0) ? w0 : (b == 1) ? w1 : w2;
    const float* src = w + (size_t)o * Cc * KP;   // contiguous 1152 floats
#pragma unroll
    for (int it = 0; it < 5; ++it) {
      const int idx = t + it * 256;
      if (idx < Cc * KP) wl[idx] = f2bf(src[idx]);   // wl[c*9+kk]
    }
    __syncthreads();
#pragma unroll
    for (int it = 0; it < 5; ++it) {
      const int idx = t + it * 256;          // kk*128 + c
      if (idx < Cc * KP) {
        const int kk = idx >> 7;
        const int c = idx & 127;
        wt[((size_t)(b * KP + kk) * Oo + o) * Cc + c] = wl[c * KP + kk];
      }
    }
  }
}

#define LDXC 136          // 128 + 8 shorts pad -> 2-way bank aliasing (free)
#define HALO_COLS 66      // w in [-1, 64]
#define HALO_ROWS 4       // h in [h0-1, h0+2]

__global__ __launch_bounds__(256, 2) void conv_main(
    const unsigned short* __restrict__ xt,
    const unsigned short* __restrict__ wt,
    const float* __restrict__ depth,
    const float* __restrict__ fx,
    float* __restrict__ out) {
  __shared__ unsigned short Xs[HALO_ROWS * HALO_COLS * LDXC];  // 71808 B
  __shared__ unsigned int code32[128];                         // 512 B

  const int g = blockIdx.x;          // 512 blocks
  const int n = g >> 6;
  const int rem = g & 63;
  const int pb = rem >> 1;           // 0..31  -> row pair
  const int ob = (rem & 1) * 64;     // 0 or 64
  const int h0 = pb * 2;

  const int tid = threadIdx.x;

  // ---- stage halo tile ONCE: Xs[(hrel*66 + ww+1)][c] = xt[n, h0-1+hrel, ww, c] ----
#pragma unroll
  for (int it = 0; it < 17; ++it) {
    const int idx = tid + it * 256;          // chunks of 8 channels
    if (idx < HALO_ROWS * HALO_COLS * 16) {
      const int ch = (idx & 15) << 3;
      const int pixidx = idx >> 4;           // 0..263
      const int lc = pixidx % HALO_COLS;
      const int hrel = pixidx / HALO_COLS;
      const int hh = h0 - 1 + hrel;
      const int ww = lc - 1;
      short8 v = {0, 0, 0, 0, 0, 0, 0, 0};
      if (hh >= 0 && hh < Hh && ww >= 0 && ww < Ww)
        v = *reinterpret_cast<const short8*>(
            xt + (size_t)((n * Hh + hh) * Ww + ww) * Cc + ch);
      *reinterpret_cast<short8*>(&Xs[pixidx * LDXC + ch]) = v;
    }
  }

  // ---- depth masks ONCE: 27-bit code (3 bits per kk) per pixel ----
  if (tid < 128) {
    const int m = tid;
    const int h = h0 + (m >> 6);
    const int w = m & 63;
    const float center = depth[n * LL + h * Ww + w];
    const float fxv = fx[n];
    const float grid = center / fxv;     // PIXEL_SIZE*DILATION = 1
    const float half = 0.5f * grid;
    unsigned int packed = 0u;
#pragma unroll
    for (int kk = 0; kk < KP; ++kk) {
      const int hh = h + kk / 3 - 1;
      const int ww = w + kk % 3 - 1;
      float d = 0.0f;
      if (hh >= 0 && hh < Hh && ww >= 0 && ww < Ww) d = depth[n * LL + hh * Ww + ww];
      const float valid = (d != 0.0f && center != 0.0f) ? 1.0f : 0.0f;
      const float dm = d * valid;
      unsigned int cb = 0u;
      if (fabsf(dm - (center + grid)) <= half) cb |= 1u;
      float m1v = (fabsf(dm - center) <= half) ? 1.0f : 0.0f;
      m1v = m1v + 1.0f - valid;
      if (m1v > 1.0f) m1v = 1.0f;
      if (m1v > 0.5f) cb |= 2u;
      if (fabsf(dm - (center - grid)) <= half) cb |= 4u;
      packed |= cb << (3 * kk);
    }
    code32[m] = packed;
  }

  __syncthreads();   // the ONLY barrier

  const int lane = tid & 63;
  const int wave = tid >> 6;
  const int ln15 = lane & 15;
  const int quad = lane >> 4;
  const int hsel = wave >> 1;        // pixel row within block (0/1)
  const int m_half = hsel * 64;
  const int wc = wave & 1;

  unsigned int cd[4];
#pragma unroll
  for (int i = 0; i < 4; ++i) cd[i] = code32[m_half + i * 16 + ln15];

  const floatx4 zf4 = {0.f, 0.f, 0.f, 0.f};
  const short8 zs8 = {0, 0, 0, 0, 0, 0, 0, 0};
  floatx4 acc[4][2];
#pragma unroll
  for (int i = 0; i < 4; ++i)
#pragma unroll
    for (int j = 0; j < 2; ++j) acc[i][j] = zf4;

  // B base: o = ob + wc*32 + j*16 + ln15, k-chunk = quad*8 (+c0*32)
  const unsigned short* wbase = wt + ((size_t)(ob + wc * 32 + ln15)) * Cc + quad * 8;

#pragma unroll 1
  for (int kk = 0; kk < KP; ++kk) {
    const int dyp = kk / 3;          // 0..2  (dy + 1)
    const int dxp = kk % 3;          // 0..2  (dx + 1)
    const int hrel = hsel + dyp;     // halo row
    const int colb = ln15 + dxp;     // halo col for i=0
    const int abase = (hrel * HALO_COLS + colb) * LDXC + quad * 8;
    const unsigned short* wp = wbase + (size_t)kk * Oo * Cc;
    const int shift = 3 * kk;

#pragma unroll
    for (int c0 = 0; c0 < 4; ++c0) {
      short8 a[4];
#pragma unroll
      for (int i = 0; i < 4; ++i)
        a[i] = *reinterpret_cast<const short8*>(&Xs[abase + i * 16 * LDXC + c0 * 32]);
#pragma unroll
      for (int b = 0; b < 3; ++b) {
        const unsigned short* wpb = wp + (size_t)b * KP * Oo * Cc + c0 * 32;
        const short8 bf0 = *reinterpret_cast<const short8*>(wpb);
        const short8 bf1 = *reinterpret_cast<const short8*>(wpb + 16 * Cc);
#pragma unroll
        for (int i = 0; i < 4; ++i) {
          short8 af = (((cd[i] >> (shift + b)) & 1u) != 0u) ? a[i] : zs8;
          acc[i][0] = __builtin_amdgcn_mfma_f32_16x16x32_bf16(af, bf0, acc[i][0], 0, 0, 0);
          acc[i][1] = __builtin_amdgcn_mfma_f32_16x16x32_bf16(af, bf1, acc[i][1], 0, 0, 0);
        }
      }
    }
  }

  // ---- epilogue: D row = m (quad*4+reg), col = o (lane&15) ----
#pragma unroll
  for (int i = 0; i < 4; ++i) {
    const int m = m_half + i * 16 + quad * 4;
    const int h = h0 + (m >> 6);
    const int w = m & 63;
#pragma unroll
    for (int j = 0; j < 2; ++j) {
      const int o = ob + wc * 32 + j * 16 + ln15;
      float* dst = out + (size_t)(n * Oo + o) * LL + h * Ww + w;
      *reinterpret_cast<floatx4*>(dst) = acc[i][j];
    }
  }
}

extern "C" void kernel_launch(void* const* d_in, const int* in_sizes, int n_in,
                              void* d_out, int out_size, void* d_ws, size_t ws_size,
                              hipStream_t stream) {
  const float* x     = (const float*)d_in[0];
  const float* depth = (const float*)d_in[1];
  const float* fx    = (const float*)d_in[2];
  const float* w0    = (const float*)d_in[3];
  const float* w1    = (const float*)d_in[4];
  const float* w2    = (const float*)d_in[5];
  float* out = (float*)d_out;

  // ws layout: xt (8*64*64*128 bf16 = 8 MB) | wt (3*9*128*128 bf16 = 0.88 MB)
  unsigned short* xt = (unsigned short*)d_ws;
  unsigned short* wt = xt + (size_t)Nn * Hh * Ww * Cc;

  prep_all<<<Nn * Hh + 3 * Oo, 256, 0, stream>>>(x, w0, w1, w2, xt, wt);
  conv_main<<<512, 256, 0, stream>>>(xt, wt, depth, fx, out);
}

// Round 3
// 138.810 us; speedup vs baseline: 1.0432x; 1.0061x over previous
//
#include <hip/hip_runtime.h>
#include <hip/hip_bf16.h>
#include <cstdint>
#include <cstddef>

#define Nn 8
#define Cc 128
#define Oo 128
#define Hh 64
#define Ww 64
#define LL (Hh * Ww)
#define KP 9

typedef __attribute__((ext_vector_type(8))) short short8;
typedef __attribute__((ext_vector_type(4))) float floatx4;
typedef __attribute__((ext_vector_type(4))) int intx4;

__device__ __forceinline__ unsigned short f2bf(float f) {
  unsigned int u = __float_as_uint(f);
  u += 0x7fffu + ((u >> 16) & 1u);   // round-to-nearest-even
  return (unsigned short)(u >> 16);
}

// Fused prep:
//  blocks [0, 512):   x[n][c][h][w] fp32 -> xt[n][h][w][c] bf16
//  blocks [512, 896): w_b[o][c][3][3] fp32 -> wt[b][kk][o][c] bf16 (coalesced via LDS)
__global__ __launch_bounds__(256) void prep_all(const float* __restrict__ x,
                                                const float* __restrict__ w0,
                                                const float* __restrict__ w1,
                                                const float* __restrict__ w2,
                                                unsigned short* __restrict__ xt,
                                                unsigned short* __restrict__ wt) {
  __shared__ float tile[Cc][Ww + 1];
  __shared__ unsigned short wl[Cc * KP];
  const int bid = blockIdx.x;
  const int t = threadIdx.x;
  if (bid < Nn * Hh) {
    const int n = bid >> 6;
    const int h = bid & 63;
    const float* src = x + (size_t)n * Cc * LL + (size_t)h * Ww;
#pragma unroll
    for (int it = 0; it < 8; ++it) {
      const int idx = t + it * 256;          // 0..2047
      const int c = idx >> 4;
      const int w4 = (idx & 15) << 2;
      const float4 v = *reinterpret_cast<const float4*>(src + (size_t)c * LL + w4);
      tile[c][w4 + 0] = v.x; tile[c][w4 + 1] = v.y;
      tile[c][w4 + 2] = v.z; tile[c][w4 + 3] = v.w;
    }
    __syncthreads();
    unsigned short* dst = xt + (size_t)((n * Hh + h) * Ww) * Cc;
#pragma unroll
    for (int it = 0; it < 4; ++it) {
      const int idx = t + it * 256;          // 0..1023
      const int w = idx >> 4;
      const int ch = (idx & 15) << 3;
      short8 v;
#pragma unroll
      for (int q = 0; q < 8; ++q)
        ((unsigned short*)&v)[q] = f2bf(tile[ch + q][w]);
      *reinterpret_cast<short8*>(dst + (size_t)w * Cc + ch) = v;
    }
  } else {
    const int bo = bid - Nn * Hh;            // 0..383
    const int b = bo >> 7;
    const int o = bo & 127;
    const float* w = (b == 0) ? w0 : (b == 1) ? w1 : w2;
    const float* src = w + (size_t)o * Cc * KP;   // contiguous 1152 floats
#pragma unroll
    for (int it = 0; it < 5; ++it) {
      const int idx = t + it * 256;
      if (idx < Cc * KP) wl[idx] = f2bf(src[idx]);   // wl[c*9+kk]
    }
    __syncthreads();
#pragma unroll
    for (int it = 0; it < 5; ++it) {
      const int idx = t + it * 256;          // kk*128 + c
      if (idx < Cc * KP) {
        const int kk = idx >> 7;
        const int c = idx & 127;
        wt[((size_t)(b * KP + kk) * Oo + o) * Cc + c] = wl[c * KP + kk];
      }
    }
  }
}

#define LDXC 136          // 128 + 8 shorts pad -> conflict-free b128 reads
#define HALO_COLS 66      // w in [-1, 64]
#define HALO_ROWS 4       // h in [h0-1, h0+2]
#define NSTEP 36          // 9 kk x 4 c0-chunks

__global__ __launch_bounds__(256, 2) void conv_main(
    const unsigned short* __restrict__ xt,
    const unsigned short* __restrict__ wt,
    const float* __restrict__ depth,
    const float* __restrict__ fx,
    float* __restrict__ out) {
  __shared__ unsigned short Xs[HALO_ROWS * HALO_COLS * LDXC];  // 71808 B
  __shared__ unsigned int code32[128];                         // 512 B

  const int g = blockIdx.x;          // 512 blocks
  const int n = g >> 6;
  const int rem = g & 63;
  const int pb = rem >> 1;           // 0..31  -> row pair
  const int ob = (rem & 1) * 64;     // 0 or 64
  const int h0 = pb * 2;

  const int tid = threadIdx.x;
  const int lane = tid & 63;
  const int wave = tid >> 6;
  const int ln15 = lane & 15;
  const int quad = lane >> 4;
  const int hsel = wave >> 1;        // pixel row within block (0/1)
  const int m_half = hsel * 64;
  const int wc = wave & 1;

  // B base: o = ob + wc*32 + j*16 + ln15, k-chunk = quad*8 (+c0*32)
  const unsigned short* wj0 = wt + (size_t)(ob + wc * 32 + ln15) * Cc + quad * 8;

  short8 Bbuf[4][6];   // rotating 4-stage prefetch buffer, 6 frags (b x j) each
  short8 Abuf[2][4];

  auto loadB = [&](int t_, short8* dst) {
    const int kk = t_ >> 2, c0 = t_ & 3;
    const size_t off = (size_t)kk * (Oo * Cc) + c0 * 32;
#pragma unroll
    for (int b = 0; b < 3; ++b) {
      dst[b * 2 + 0] = *reinterpret_cast<const short8*>(wj0 + (size_t)b * (KP * Oo * Cc) + off);
      dst[b * 2 + 1] = *reinterpret_cast<const short8*>(wj0 + (size_t)b * (KP * Oo * Cc) + 16 * Cc + off);
    }
  };
  auto loadA = [&](int t_, short8* dst) {
    const int kk = t_ >> 2, c0 = t_ & 3;
    const int dyp = kk / 3, dxp = kk % 3;
    const int abase = ((hsel + dyp) * HALO_COLS + ln15 + dxp) * LDXC + quad * 8 + c0 * 32;
#pragma unroll
    for (int i = 0; i < 4; ++i)
      dst[i] = *reinterpret_cast<const short8*>(&Xs[abase + i * 16 * LDXC]);
  };

  // ---- issue B prologue loads FIRST: their L2 latency overlaps halo staging ----
  loadB(0, Bbuf[0]);
  loadB(1, Bbuf[1]);
  loadB(2, Bbuf[2]);

  // ---- stage halo tile ONCE: Xs[(hrel*66 + ww+1)][c] = xt[n, h0-1+hrel, ww, c] ----
#pragma unroll
  for (int it = 0; it < 17; ++it) {
    const int idx = tid + it * 256;          // chunks of 8 channels
    if (idx < HALO_ROWS * HALO_COLS * 16) {
      const int ch = (idx & 15) << 3;
      const int pixidx = idx >> 4;           // 0..263
      const int lc = pixidx % HALO_COLS;
      const int hrel = pixidx / HALO_COLS;
      const int hh = h0 - 1 + hrel;
      const int ww = lc - 1;
      short8 v = {0, 0, 0, 0, 0, 0, 0, 0};
      if (hh >= 0 && hh < Hh && ww >= 0 && ww < Ww)
        v = *reinterpret_cast<const short8*>(
            xt + (size_t)((n * Hh + hh) * Ww + ww) * Cc + ch);
      *reinterpret_cast<short8*>(&Xs[pixidx * LDXC + ch]) = v;
    }
  }

  // ---- depth masks ONCE: 27-bit code (3 bits per kk) per pixel ----
  if (tid < 128) {
    const int m = tid;
    const int h = h0 + (m >> 6);
    const int w = m & 63;
    const float center = depth[n * LL + h * Ww + w];
    const float fxv = fx[n];
    const float grid = center / fxv;     // PIXEL_SIZE*DILATION = 1
    const float half = 0.5f * grid;
    unsigned int packed = 0u;
#pragma unroll
    for (int kk = 0; kk < KP; ++kk) {
      const int hh = h + kk / 3 - 1;
      const int ww = w + kk % 3 - 1;
      float d = 0.0f;
      if (hh >= 0 && hh < Hh && ww >= 0 && ww < Ww) d = depth[n * LL + hh * Ww + ww];
      const float valid = (d != 0.0f && center != 0.0f) ? 1.0f : 0.0f;
      const float dm = d * valid;
      unsigned int cb = 0u;
      if (fabsf(dm - (center + grid)) <= half) cb |= 1u;
      float m1v = (fabsf(dm - center) <= half) ? 1.0f : 0.0f;
      m1v = m1v + 1.0f - valid;
      if (m1v > 1.0f) m1v = 1.0f;
      if (m1v > 0.5f) cb |= 2u;
      if (fabsf(dm - (center - grid)) <= half) cb |= 4u;
      packed |= cb << (3 * kk);
    }
    code32[m] = packed;
  }

  __syncthreads();   // the ONLY barrier

  unsigned int cd[4];
#pragma unroll
  for (int i = 0; i < 4; ++i) cd[i] = code32[m_half + i * 16 + ln15];

  const floatx4 zf4 = {0.f, 0.f, 0.f, 0.f};
  floatx4 acc[4][2];
#pragma unroll
  for (int i = 0; i < 4; ++i)
#pragma unroll
    for (int j = 0; j < 2; ++j) acc[i][j] = zf4;

  loadA(0, Abuf[0]);

  // ---- fully unrolled software pipeline: B 3 steps ahead, A 1 step ahead ----
#pragma unroll
  for (int t = 0; t < NSTEP; ++t) {
    if (t + 3 < NSTEP) loadB(t + 3, Bbuf[(t + 3) & 3]);
    if (t + 1 < NSTEP) loadA(t + 1, Abuf[(t + 1) & 1]);
    const int kk = t >> 2;
    const int shift = 3 * kk;
    const short8* B = Bbuf[t & 3];
    const short8* A = Abuf[t & 1];
#pragma unroll
    for (int b = 0; b < 3; ++b) {
#pragma unroll
      for (int i = 0; i < 4; ++i) {
        // af = A[i] & sext(mask bit) — 1 bfe + 4 vector ANDs, no vcc traffic
        const int msk = -(int)((cd[i] >> (shift + b)) & 1u);
        intx4 a4 = *reinterpret_cast<const intx4*>(&A[i]);
        intx4 m4 = {msk, msk, msk, msk};
        a4 &= m4;
        const short8 af = *reinterpret_cast<const short8*>(&a4);
        acc[i][0] = __builtin_amdgcn_mfma_f32_16x16x32_bf16(af, B[b * 2 + 0], acc[i][0], 0, 0, 0);
        acc[i][1] = __builtin_amdgcn_mfma_f32_16x16x32_bf16(af, B[b * 2 + 1], acc[i][1], 0, 0, 0);
      }
    }
  }

  // ---- epilogue: D row = m (quad*4+reg), col = o (lane&15) ----
#pragma unroll
  for (int i = 0; i < 4; ++i) {
    const int m = m_half + i * 16 + quad * 4;
    const int h = h0 + (m >> 6);
    const int w = m & 63;
#pragma unroll
    for (int j = 0; j < 2; ++j) {
      const int o = ob + wc * 32 + j * 16 + ln15;
      float* dst = out + (size_t)(n * Oo + o) * LL + h * Ww + w;
      *reinterpret_cast<floatx4*>(dst) = acc[i][j];
    }
  }
}

extern "C" void kernel_launch(void* const* d_in, const int* in_sizes, int n_in,
                              void* d_out, int out_size, void* d_ws, size_t ws_size,
                              hipStream_t stream) {
  const float* x     = (const float*)d_in[0];
  const float* depth = (const float*)d_in[1];
  const float* fx    = (const float*)d_in[2];
  const float* w0    = (const float*)d_in[3];
  const float* w1    = (const float*)d_in[4];
  const float* w2    = (const float*)d_in[5];
  float* out = (float*)d_out;

  // ws layout: xt (8*64*64*128 bf16 = 8 MB) | wt (3*9*128*128 bf16 = 0.88 MB)
  unsigned short* xt = (unsigned short*)d_ws;
  unsigned short* wt = xt + (size_t)Nn * Hh * Ww * Cc;

  prep_all<<<Nn * Hh + 3 * Oo, 256, 0, stream>>>(x, w0, w1, w2, xt, wt);
  conv_main<<<512, 256, 0, stream>>>(xt, wt, depth, fx, out);
}

// Round 4
// 116.691 us; speedup vs baseline: 1.2410x; 1.1896x over previous
//
#include <hip/hip_runtime.h>
#include <hip/hip_bf16.h>
#include <cstdint>
#include <cstddef>

#define Nn 8
#define Cc 128
#define Oo 128
#define Hh 64
#define Ww 64
#define LL (Hh * Ww)
#define KP 9

typedef __attribute__((ext_vector_type(8))) short short8;
typedef __attribute__((ext_vector_type(4))) float floatx4;
typedef __attribute__((ext_vector_type(4))) int intx4;

#define SGB(m, s, i) __builtin_amdgcn_sched_group_barrier(m, s, i)

__device__ __forceinline__ unsigned short f2bf(float f) {
  unsigned int u = __float_as_uint(f);
  u += 0x7fffu + ((u >> 16) & 1u);   // round-to-nearest-even
  return (unsigned short)(u >> 16);
}

// Fused prep:
//  blocks [0, 512):   x[n][c][h][w] fp32 -> xt[n][h][w][c] bf16
//  blocks [512, 896): w_b[o][c][3][3] fp32 -> wt2 fragment-contiguous bf16:
//    wt2[((b*9+kk)*4+c0)*4096 + ob1*2048 + wc*1024 + j*512 + ln15*32 + c%32]
//    so one wave's B fragment load = 1 KB fully contiguous.
__global__ __launch_bounds__(256) void prep_all(const float* __restrict__ x,
                                                const float* __restrict__ w0,
                                                const float* __restrict__ w1,
                                                const float* __restrict__ w2,
                                                unsigned short* __restrict__ xt,
                                                unsigned short* __restrict__ wt2) {
  __shared__ float tile[Cc][Ww + 1];
  __shared__ unsigned short wl[Cc * KP];
  const int bid = blockIdx.x;
  const int t = threadIdx.x;
  if (bid < Nn * Hh) {
    const int n = bid >> 6;
    const int h = bid & 63;
    const float* src = x + (size_t)n * Cc * LL + (size_t)h * Ww;
#pragma unroll
    for (int it = 0; it < 8; ++it) {
      const int idx = t + it * 256;          // 0..2047
      const int c = idx >> 4;
      const int w4 = (idx & 15) << 2;
      const float4 v = *reinterpret_cast<const float4*>(src + (size_t)c * LL + w4);
      tile[c][w4 + 0] = v.x; tile[c][w4 + 1] = v.y;
      tile[c][w4 + 2] = v.z; tile[c][w4 + 3] = v.w;
    }
    __syncthreads();
    unsigned short* dst = xt + (size_t)((n * Hh + h) * Ww) * Cc;
#pragma unroll
    for (int it = 0; it < 4; ++it) {
      const int idx = t + it * 256;          // 0..1023
      const int w = idx >> 4;
      const int ch = (idx & 15) << 3;
      short8 v;
#pragma unroll
      for (int q = 0; q < 8; ++q)
        ((unsigned short*)&v)[q] = f2bf(tile[ch + q][w]);
      *reinterpret_cast<short8*>(dst + (size_t)w * Cc + ch) = v;
    }
  } else {
    const int bo = bid - Nn * Hh;            // 0..383
    const int b = bo >> 7;
    const int o = bo & 127;
    const float* w = (b == 0) ? w0 : (b == 1) ? w1 : w2;
    const float* src = w + (size_t)o * Cc * KP;   // contiguous 1152 floats
#pragma unroll
    for (int it = 0; it < 5; ++it) {
      const int idx = t + it * 256;
      if (idx < Cc * KP) wl[idx] = f2bf(src[idx]);   // wl[c*9+kk]
    }
    __syncthreads();
    const int obase = ((o >> 6) & 1) * 2048 + ((o >> 5) & 1) * 1024 +
                      ((o >> 4) & 1) * 512 + (o & 15) * 32;
#pragma unroll
    for (int it = 0; it < 5; ++it) {
      const int idx = t + it * 256;          // 0..1151 = kk*128 + c
      if (idx < Cc * KP) {
        const int kk = idx >> 7;
        const int c = idx & 127;
        const int c0 = c >> 5;
        const int cc = c & 31;
        wt2[(size_t)(b * 36 + kk * 4 + c0) * 4096 + obase + cc] = wl[c * KP + kk];
      }
    }
  }
}

#define LDXC 132          // pixel stride 264 B = 66 words ≡ 2 mod 32 -> 2-way (free)
#define HALO_COLS 66      // w in [-1, 64]
#define HALO_ROWS 4       // h in [h0-1, h0+2]
#define NSTEP 36          // 9 kk x 4 c0-chunks

__global__ __launch_bounds__(256, 2) void conv_main(
    const unsigned short* __restrict__ xt,
    const unsigned short* __restrict__ wt2,
    const float* __restrict__ depth,
    const float* __restrict__ fx,
    float* __restrict__ out) {
  __shared__ unsigned short Xs[HALO_ROWS * HALO_COLS * LDXC];  // 69696 B
  __shared__ unsigned int code32[128];                         // 512 B

  const int g = blockIdx.x;          // 512 blocks
  const int n = g >> 6;
  const int rem = g & 63;
  const int pb = rem >> 1;           // 0..31  -> row pair
  const int ob1 = rem & 1;           // o-half
  const int h0 = pb * 2;

  const int tid = threadIdx.x;
  const int lane = tid & 63;
  const int wave = tid >> 6;
  const int ln15 = lane & 15;
  const int quad = lane >> 4;
  const int hsel = wave >> 1;        // pixel row within block (0/1)
  const int m_half = hsel * 64;
  const int wc = wave & 1;

  // fragment-contiguous B base for this wave
  const unsigned short* wfrag = wt2 + (size_t)(ob1 * 2048 + wc * 1024 + ln15 * 32 + quad * 8);

  short8 B0[6], B1[6], B2[6];
  short8 A0[4], A1[4], A2[4];

#define LOADB(DST, S)                                                           \
  {                                                                             \
    int sp = (S); if (sp >= NSTEP) sp -= NSTEP;                                 \
    const unsigned short* bp = wfrag + (size_t)((sp >> 2) * 4 + (sp & 3)) * 4096; \
    DST[0] = *reinterpret_cast<const short8*>(bp);                              \
    DST[1] = *reinterpret_cast<const short8*>(bp + 512);                        \
    DST[2] = *reinterpret_cast<const short8*>(bp + 147456);                     \
    DST[3] = *reinterpret_cast<const short8*>(bp + 147456 + 512);               \
    DST[4] = *reinterpret_cast<const short8*>(bp + 294912);                     \
    DST[5] = *reinterpret_cast<const short8*>(bp + 294912 + 512);               \
  }

#define LOADA(DST, S)                                                           \
  {                                                                             \
    int sp = (S); if (sp >= NSTEP) sp -= NSTEP;                                 \
    const int kkp = sp >> 2, c0p = sp & 3;                                      \
    const int dyp = kkp / 3, dxp = kkp % 3;                                     \
    const int ab = ((hsel + dyp) * HALO_COLS + ln15 + dxp) * LDXC + quad * 8 + c0p * 32; \
    DST[0] = *reinterpret_cast<const short8*>(&Xs[ab]);                         \
    DST[1] = *reinterpret_cast<const short8*>(&Xs[ab + 16 * LDXC]);             \
    DST[2] = *reinterpret_cast<const short8*>(&Xs[ab + 32 * LDXC]);             \
    DST[3] = *reinterpret_cast<const short8*>(&Xs[ab + 48 * LDXC]);             \
  }

  // ---- B prologue loads FIRST: L2 latency overlaps halo staging ----
  LOADB(B0, 0)
  LOADB(B1, 1)

  // ---- stage halo tile ONCE: Xs[(hrel*66 + ww+1)][c] = xt[n, h0-1+hrel, ww, c] ----
#pragma unroll
  for (int it = 0; it < 17; ++it) {
    const int idx = tid + it * 256;          // chunks of 8 channels
    if (idx < HALO_ROWS * HALO_COLS * 16) {
      const int ch = (idx & 15) << 3;
      const int pixidx = idx >> 4;           // 0..263
      const int lc = pixidx % HALO_COLS;
      const int hrel = pixidx / HALO_COLS;
      const int hh = h0 - 1 + hrel;
      const int ww = lc - 1;
      short8 v = {0, 0, 0, 0, 0, 0, 0, 0};
      if (hh >= 0 && hh < Hh && ww >= 0 && ww < Ww)
        v = *reinterpret_cast<const short8*>(
            xt + (size_t)((n * Hh + hh) * Ww + ww) * Cc + ch);
      *reinterpret_cast<short8*>(&Xs[pixidx * LDXC + ch]) = v;
    }
  }

  // ---- depth masks ONCE: 27-bit code (3 bits per kk) per pixel ----
  if (tid < 128) {
    const int m = tid;
    const int h = h0 + (m >> 6);
    const int w = m & 63;
    const float center = depth[n * LL + h * Ww + w];
    const float fxv = fx[n];
    const float grid = center / fxv;     // PIXEL_SIZE*DILATION = 1
    const float half = 0.5f * grid;
    unsigned int packed = 0u;
#pragma unroll
    for (int kk = 0; kk < KP; ++kk) {
      const int hh = h + kk / 3 - 1;
      const int ww = w + kk % 3 - 1;
      float d = 0.0f;
      if (hh >= 0 && hh < Hh && ww >= 0 && ww < Ww) d = depth[n * LL + hh * Ww + ww];
      const float valid = (d != 0.0f && center != 0.0f) ? 1.0f : 0.0f;
      const float dm = d * valid;
      unsigned int cb = 0u;
      if (fabsf(dm - (center + grid)) <= half) cb |= 1u;
      float m1v = (fabsf(dm - center) <= half) ? 1.0f : 0.0f;
      m1v = m1v + 1.0f - valid;
      if (m1v > 1.0f) m1v = 1.0f;
      if (m1v > 0.5f) cb |= 2u;
      if (fabsf(dm - (center - grid)) <= half) cb |= 4u;
      packed |= cb << (3 * kk);
    }
    code32[m] = packed;
  }

  __syncthreads();   // the ONLY barrier

  unsigned int cd[4];
#pragma unroll
  for (int i = 0; i < 4; ++i) cd[i] = code32[m_half + i * 16 + ln15];

  const floatx4 zf4 = {0.f, 0.f, 0.f, 0.f};
  floatx4 acc[4][2];
#pragma unroll
  for (int i = 0; i < 4; ++i)
#pragma unroll
    for (int j = 0; j < 2; ++j) acc[i][j] = zf4;

  LOADA(A0, 0)

  // One pipeline step: compute with slot CUR, prefetch A(s+1)->slot AN, B(s+2)->slot BN.
  // sched_group_barrier template pins: [6 VMEM][4 DS][(5 VALU, 2 MFMA) x12] per step.
#define STEP(ACUR, BCUR, AN, BN)                                                \
  {                                                                             \
    const int kk = s >> 2;                                                      \
    const int shift = 3 * kk;                                                   \
    LOADB(BN, s + 2)                                                            \
    LOADA(AN, s + 1)                                                            \
    _Pragma("unroll")                                                           \
    for (int b = 0; b < 3; ++b) {                                               \
      _Pragma("unroll")                                                         \
      for (int i = 0; i < 4; ++i) {                                             \
        const int msk = __builtin_amdgcn_sbfe((int)cd[i], shift + b, 1);        \
        intx4 a4 = *reinterpret_cast<const intx4*>(&ACUR[i]);                   \
        intx4 m4 = {msk, msk, msk, msk};                                        \
        a4 &= m4;                                                               \
        const short8 af = *reinterpret_cast<const short8*>(&a4);                \
        acc[i][0] = __builtin_amdgcn_mfma_f32_16x16x32_bf16(af, BCUR[b * 2 + 0], acc[i][0], 0, 0, 0); \
        acc[i][1] = __builtin_amdgcn_mfma_f32_16x16x32_bf16(af, BCUR[b * 2 + 1], acc[i][1], 0, 0, 0); \
      }                                                                         \
    }                                                                           \
    SGB(0x020, 6, 0);                                                           \
    SGB(0x100, 4, 0);                                                           \
    _Pragma("unroll")                                                           \
    for (int q = 0; q < 12; ++q) { SGB(0x002, 5, 0); SGB(0x008, 2, 0); }        \
    s += 1;                                                                     \
  }

#pragma unroll 1
  for (int tt = 0; tt < 12; ++tt) {
    int s = 3 * tt;
    STEP(A0, B0, A1, B2)
    STEP(A1, B1, A2, B0)
    STEP(A2, B2, A0, B1)
  }
#undef STEP

  // ---- epilogue: D row = m (quad*4+reg), col = o (lane&15) ----
#pragma unroll
  for (int i = 0; i < 4; ++i) {
    const int m = m_half + i * 16 + quad * 4;
    const int h = h0 + (m >> 6);
    const int w = m & 63;
#pragma unroll
    for (int j = 0; j < 2; ++j) {
      const int o = ob1 * 64 + wc * 32 + j * 16 + ln15;
      float* dst = out + (size_t)(n * Oo + o) * LL + h * Ww + w;
      *reinterpret_cast<floatx4*>(dst) = acc[i][j];
    }
  }
}

extern "C" void kernel_launch(void* const* d_in, const int* in_sizes, int n_in,
                              void* d_out, int out_size, void* d_ws, size_t ws_size,
                              hipStream_t stream) {
  const float* x     = (const float*)d_in[0];
  const float* depth = (const float*)d_in[1];
  const float* fx    = (const float*)d_in[2];
  const float* w0    = (const float*)d_in[3];
  const float* w1    = (const float*)d_in[4];
  const float* w2    = (const float*)d_in[5];
  float* out = (float*)d_out;

  // ws layout: xt (8*64*64*128 bf16 = 8 MB) | wt2 (3*9*128*128 bf16 = 0.88 MB)
  unsigned short* xt = (unsigned short*)d_ws;
  unsigned short* wt2 = xt + (size_t)Nn * Hh * Ww * Cc;

  prep_all<<<Nn * Hh + 3 * Oo, 256, 0, stream>>>(x, w0, w1, w2, xt, wt2);
  conv_main<<<512, 256, 0, stream>>>(xt, wt2, depth, fx, out);
}